// Round 2
// baseline (1392.159 us; speedup 1.0000x reference)
//
#include <hip/hip_runtime.h>
#include <hip/hip_bf16.h>
#include <math.h>

#define D 2048
#define NH 16
#define KHD 8
#define HD 128
#define T_NOISE 1024
#define T_PAD 1024
#define MAX_KV 4096
#define SM_SCALE 0.08838834764831845f  /* 1/sqrt(128) */

// ---------------------------------------------------------------------------
// Generic tiled f32 GEMM: C[M,N] = A[M,D] * B[D,N].
// A row r comes from A0 if r < splitM else A1[r - splitM] (concat support).
// 64x64 tile, BK=16, 256 threads, 4x4 microtile.
// ---------------------------------------------------------------------------
__global__ __launch_bounds__(256)
void gemm_f32(const float* __restrict__ A0, const float* __restrict__ A1,
              int splitM, const float* __restrict__ B, float* __restrict__ C,
              int M, int N) {
    __shared__ float As[64][17];   // +1 pad: conflict-free column reads
    __shared__ float Bs[16][64];
    int tid = threadIdx.x;
    int ty = tid >> 4, tx = tid & 15;
    int row0 = blockIdx.y * 64, col0 = blockIdx.x * 64;
    float acc[4][4] = {};

    int ar = tid >> 2, akq = (tid & 3) << 2;     // A: 64 rows x 4 float4
    int garow = row0 + ar;
    const float* arow_ptr = (garow < splitM)
        ? (A0 + (size_t)garow * D)
        : (A1 + (size_t)(garow - splitM) * D);
    int br = tid >> 4, bc = (tid & 15) << 2;     // B: 16 rows x 16 float4

    for (int k0 = 0; k0 < D; k0 += 16) {
        float4 av = *(const float4*)(arow_ptr + k0 + akq);
        As[ar][akq + 0] = av.x; As[ar][akq + 1] = av.y;
        As[ar][akq + 2] = av.z; As[ar][akq + 3] = av.w;
        *(float4*)&Bs[br][bc] = *(const float4*)(B + (size_t)(k0 + br) * N + col0 + bc);
        __syncthreads();
        #pragma unroll
        for (int kk = 0; kk < 16; ++kk) {
            float a[4], b[4];
            #pragma unroll
            for (int i = 0; i < 4; ++i) a[i] = As[ty * 4 + i][kk];
            #pragma unroll
            for (int j = 0; j < 4; ++j) b[j] = Bs[kk][tx * 4 + j];
            #pragma unroll
            for (int i = 0; i < 4; ++i)
                #pragma unroll
                for (int j = 0; j < 4; ++j)
                    acc[i][j] += a[i] * b[j];
        }
        __syncthreads();
    }
    #pragma unroll
    for (int i = 0; i < 4; ++i) {
        float4 v = make_float4(acc[i][0], acc[i][1], acc[i][2], acc[i][3]);
        *(float4*)(C + (size_t)(row0 + ty * 4 + i) * N + col0 + tx * 4) = v;
    }
}

// ---------------------------------------------------------------------------
// Fused RMSNorm + RoPE, in place. One block (128 threads) per 128-elem row.
// Row r belongs to token t = r / hpt; position = posA[t] if t<splitT else
// posB[t-splitT].
// ---------------------------------------------------------------------------
__global__ __launch_bounds__(128)
void rmsrope(float* __restrict__ x, int hpt,
             const int* __restrict__ posA, const int* __restrict__ posB,
             int splitT, const float* __restrict__ scale) {
    __shared__ float red[128];
    __shared__ float nrm[128];
    int row = blockIdx.x;
    int h = threadIdx.x;
    float v = x[(size_t)row * HD + h];
    red[h] = v * v;
    __syncthreads();
    #pragma unroll
    for (int off = 64; off > 0; off >>= 1) {
        if (h < off) red[h] += red[h + off];
        __syncthreads();
    }
    float inv = rsqrtf(red[0] * (1.0f / 128.0f) + 1e-6f);
    nrm[h] = v * inv * scale[h];
    __syncthreads();
    if (h < 64) {
        int t = row / hpt;
        int pos = (t < splitT) ? posA[t] : posB[t - splitT];
        // inv_freq = THETA^(-h/64) = exp(-h * ln(1e6) / 64)
        float inv_freq = expf((float)h * (-13.815510557964274f / 64.0f));
        float ang = (float)pos * inv_freq;
        float c = cosf(ang), s = sinf(ang);
        float x1 = nrm[h], x2 = nrm[h + 64];
        x[(size_t)row * HD + h]      = x1 * c - x2 * s;
        x[(size_t)row * HD + h + 64] = x2 * c + x1 * s;
    }
}

// ---------------------------------------------------------------------------
// Build the output KV caches: copy unchanged regions from input caches and
// scatter the new ctx / noise K,V (with GQA repeat n -> n>>1).
// One thread per float4; total 16*4096*32 float4 per cache.
// ---------------------------------------------------------------------------
__global__ __launch_bounds__(256)
void cache_scatter(const float* __restrict__ in_k, const float* __restrict__ in_v,
                   const float* __restrict__ k_rot, const float* __restrict__ v_new,
                   float* __restrict__ out_k, float* __restrict__ out_v,
                   const int* __restrict__ clp, const int* __restrict__ acp) {
    int cache_len = clp[0], actx = acp[0];
    int noise_start = cache_len + actx;
    int i = blockIdx.x * 256 + threadIdx.x;   // float4 index
    int n = i >> 17;                          // / (4096*32)
    int rem = i & 131071;
    int pos = rem >> 5;
    int h4 = (rem & 31) << 2;
    size_t co = ((size_t)(n * MAX_KV + pos)) * HD + h4;
    float4 kv, vv;
    if (pos >= noise_start && pos < noise_start + T_NOISE) {
        int srow = T_PAD + (pos - noise_start);
        size_t so = ((size_t)srow * KHD + (n >> 1)) * HD + h4;
        kv = *(const float4*)(k_rot + so);
        vv = *(const float4*)(v_new + so);
    } else if (pos >= cache_len && pos < cache_len + T_PAD) {
        int t = pos - cache_len;
        if (t < actx) {
            size_t so = ((size_t)t * KHD + (n >> 1)) * HD + h4;
            kv = *(const float4*)(k_rot + so);
            vv = *(const float4*)(v_new + so);
        } else {
            kv = make_float4(0.f, 0.f, 0.f, 0.f);
            vv = kv;
        }
    } else {
        kv = *(const float4*)(in_k + co);
        vv = *(const float4*)(in_v + co);
    }
    *(float4*)(out_k + co) = kv;
    *(float4*)(out_v + co) = vv;
}

// ---------------------------------------------------------------------------
// Flash attention (f32, online softmax). Block = 256 threads handles one head
// and a 16-row q tile; kv processed in tiles of 32. No causal mask; positions
// >= new_len masked to -1e30.
// Score phase: thread (r = tid>>4, c = tid&15) computes S[r][c], S[r][c+16].
// PV phase:    thread (r, hs = (tid&15)*8) accumulates O[r][hs..hs+8).
// ---------------------------------------------------------------------------
__global__ __launch_bounds__(256)
void flash_attn(const float* __restrict__ qrot, const float* __restrict__ kc,
                const float* __restrict__ vc, float* __restrict__ aout,
                const int* __restrict__ clp, const int* __restrict__ acp) {
    __shared__ float q_s[16][132];
    __shared__ float k_s[32][132];
    __shared__ float v_s[32][128];
    __shared__ float p_s[16][36];
    int n = blockIdx.y;
    int q0 = blockIdx.x * 16;
    int tid = threadIdx.x;
    int new_len = clp[0] + acp[0] + T_NOISE;

    #pragma unroll
    for (int i = 0; i < 8; ++i) {          // 16x128 q tile
        int idx = tid + i * 256;
        int r = idx >> 7, h = idx & 127;
        q_s[r][h] = qrot[((size_t)(q0 + r) * NH + n) * HD + h];
    }
    int r_g = tid >> 4;
    int c_g = tid & 15;
    int hs = c_g << 3;
    float acc[8] = {};
    float m = -INFINITY, l = 0.0f;
    int ntiles = (new_len + 31) >> 5;
    const float* kbase = kc + (size_t)n * MAX_KV * HD;
    const float* vbase = vc + (size_t)n * MAX_KV * HD;
    __syncthreads();

    for (int t = 0; t < ntiles; ++t) {
        int pos0 = t << 5;
        #pragma unroll
        for (int i = 0; i < 4; ++i) {      // stage 32x128 K and V tiles
            int idx = tid + i * 256;       // 32 rows x 32 float4
            int kv = idx >> 5, f4 = (idx & 31) << 2;
            *(float4*)&k_s[kv][f4] = *(const float4*)(kbase + (size_t)(pos0 + kv) * HD + f4);
            *(float4*)&v_s[kv][f4] = *(const float4*)(vbase + (size_t)(pos0 + kv) * HD + f4);
        }
        __syncthreads();

        float sc0 = 0.f, sc1 = 0.f;
        #pragma unroll 8
        for (int h = 0; h < 128; ++h) {
            float qv = q_s[r_g][h];
            sc0 += qv * k_s[c_g][h];
            sc1 += qv * k_s[c_g + 16][h];
        }
        float s0 = sc0 * SM_SCALE, s1 = sc1 * SM_SCALE;
        if (pos0 + c_g >= new_len)      s0 = -1e30f;
        if (pos0 + c_g + 16 >= new_len) s1 = -1e30f;

        float tm = fmaxf(s0, s1);
        #pragma unroll
        for (int off = 1; off < 16; off <<= 1) tm = fmaxf(tm, __shfl_xor(tm, off, 16));
        float m_new = fmaxf(m, tm);
        float alpha = expf(m - m_new);
        float p0 = expf(s0 - m_new), p1 = expf(s1 - m_new);
        float ps = p0 + p1;
        #pragma unroll
        for (int off = 1; off < 16; off <<= 1) ps += __shfl_xor(ps, off, 16);
        l = l * alpha + ps;
        m = m_new;
        p_s[r_g][c_g] = p0;
        p_s[r_g][c_g + 16] = p1;
        #pragma unroll
        for (int j = 0; j < 8; ++j) acc[j] *= alpha;
        __syncthreads();

        #pragma unroll 8
        for (int kv = 0; kv < 32; ++kv) {
            float pv = p_s[r_g][kv];
            #pragma unroll
            for (int j = 0; j < 8; ++j) acc[j] += pv * v_s[kv][hs + j];
        }
        __syncthreads();
    }
    float invl = 1.0f / l;
    #pragma unroll
    for (int j = 0; j < 8; ++j)
        aout[((size_t)(q0 + r_g) * NH + n) * HD + hs + j] = acc[j] * invl;
}

// ---------------------------------------------------------------------------
extern "C" void kernel_launch(void* const* d_in, const int* in_sizes, int n_in,
                              void* d_out, int out_size, void* d_ws, size_t ws_size,
                              hipStream_t stream) {
    const float* x_noise       = (const float*)d_in[0];
    const float* target_hidden = (const float*)d_in[1];
    const int*   noise_pos     = (const int*)d_in[2];
    const int*   ctx_pos       = (const int*)d_in[3];
    const float* in_k          = (const float*)d_in[4];
    const float* in_v          = (const float*)d_in[5];
    const int*   clp           = (const int*)d_in[6];
    const int*   acp           = (const int*)d_in[7];
    const float* Wq            = (const float*)d_in[8];
    const float* Wk            = (const float*)d_in[9];
    const float* Wv            = (const float*)d_in[10];
    const float* Wo            = (const float*)d_in[11];
    const float* q_scale       = (const float*)d_in[12];
    const float* k_scale       = (const float*)d_in[13];

    float* out   = (float*)d_out;
    float* out_k = out + (size_t)T_NOISE * D;
    float* out_v = out_k + (size_t)NH * MAX_KV * HD;

    float* ws    = (float*)d_ws;
    float* q_tmp = ws;                       // 1024x2048          [0,   2M)
    float* k_tmp = ws + 2u * 1024 * 1024;    // 2048x1024          [2M,  4M)
    float* v_tmp = ws + 4u * 1024 * 1024;    // 2048x1024          [4M,  6M)  (was 3M: overlapped k_tmp!)
    float* a_out = k_tmp;                    // dead after cache_scatter; reuse

    dim3 blk(256);
    // Projections
    gemm_f32<<<dim3(2048 / 64, 1024 / 64), blk, 0, stream>>>(
        x_noise, x_noise, 1024, Wq, q_tmp, 1024, 2048);
    gemm_f32<<<dim3(1024 / 64, 2048 / 64), blk, 0, stream>>>(
        target_hidden, x_noise, 1024, Wk, k_tmp, 2048, 1024);
    gemm_f32<<<dim3(1024 / 64, 2048 / 64), blk, 0, stream>>>(
        target_hidden, x_noise, 1024, Wv, v_tmp, 2048, 1024);
    // Norm + RoPE
    rmsrope<<<1024 * 16, 128, 0, stream>>>(q_tmp, NH, noise_pos, noise_pos, 2048, q_scale);
    rmsrope<<<2048 * 8, 128, 0, stream>>>(k_tmp, KHD, ctx_pos, noise_pos, 1024, k_scale);
    // KV cache build (also copies unchanged regions)
    cache_scatter<<<8192, 256, 0, stream>>>(in_k, in_v, k_tmp, v_tmp, out_k, out_v, clp, acp);
    // Attention over the freshly written caches
    flash_attn<<<dim3(64, 16), 256, 0, stream>>>(q_tmp, out_k, out_v, a_out, clp, acp);
    // Output projection
    gemm_f32<<<dim3(2048 / 64, 1024 / 64), blk, 0, stream>>>(
        a_out, a_out, 1024, Wo, out, 1024, 2048);
}

// Round 3
// 744.478 us; speedup vs baseline: 1.8700x; 1.8700x over previous
//
#include <hip/hip_runtime.h>
#include <hip/hip_bf16.h>
#include <math.h>

#define D 2048
#define NH 16
#define KHD 8
#define HD 128
#define T_NOISE 1024
#define T_PAD 1024
#define MAX_KV 4096
#define SM_SCALE 0.08838834764831845f  /* 1/sqrt(128) */

typedef __attribute__((ext_vector_type(8))) short short8;
typedef __attribute__((ext_vector_type(4))) short short4v;
typedef __attribute__((ext_vector_type(4))) float f32x4;

// ---------------------------------------------------------------------------
// Generic tiled f32 GEMM: C[M,N] = A[M,D] * B[D,N].  (unchanged this round)
// ---------------------------------------------------------------------------
__global__ __launch_bounds__(256)
void gemm_f32(const float* __restrict__ A0, const float* __restrict__ A1,
              int splitM, const float* __restrict__ B, float* __restrict__ C,
              int M, int N) {
    __shared__ float As[64][17];
    __shared__ float Bs[16][64];
    int tid = threadIdx.x;
    int ty = tid >> 4, tx = tid & 15;
    int row0 = blockIdx.y * 64, col0 = blockIdx.x * 64;
    float acc[4][4] = {};

    int ar = tid >> 2, akq = (tid & 3) << 2;
    int garow = row0 + ar;
    const float* arow_ptr = (garow < splitM)
        ? (A0 + (size_t)garow * D)
        : (A1 + (size_t)(garow - splitM) * D);
    int br = tid >> 4, bc = (tid & 15) << 2;

    for (int k0 = 0; k0 < D; k0 += 16) {
        float4 av = *(const float4*)(arow_ptr + k0 + akq);
        As[ar][akq + 0] = av.x; As[ar][akq + 1] = av.y;
        As[ar][akq + 2] = av.z; As[ar][akq + 3] = av.w;
        *(float4*)&Bs[br][bc] = *(const float4*)(B + (size_t)(k0 + br) * N + col0 + bc);
        __syncthreads();
        #pragma unroll
        for (int kk = 0; kk < 16; ++kk) {
            float a[4], b[4];
            #pragma unroll
            for (int i = 0; i < 4; ++i) a[i] = As[ty * 4 + i][kk];
            #pragma unroll
            for (int j = 0; j < 4; ++j) b[j] = Bs[kk][tx * 4 + j];
            #pragma unroll
            for (int i = 0; i < 4; ++i)
                #pragma unroll
                for (int j = 0; j < 4; ++j)
                    acc[i][j] += a[i] * b[j];
        }
        __syncthreads();
    }
    #pragma unroll
    for (int i = 0; i < 4; ++i) {
        float4 v = make_float4(acc[i][0], acc[i][1], acc[i][2], acc[i][3]);
        *(float4*)(C + (size_t)(row0 + ty * 4 + i) * N + col0 + tx * 4) = v;
    }
}

// ---------------------------------------------------------------------------
// Fused RMSNorm + RoPE, in place. (unchanged)
// ---------------------------------------------------------------------------
__global__ __launch_bounds__(128)
void rmsrope(float* __restrict__ x, int hpt,
             const int* __restrict__ posA, const int* __restrict__ posB,
             int splitT, const float* __restrict__ scale) {
    __shared__ float red[128];
    __shared__ float nrm[128];
    int row = blockIdx.x;
    int h = threadIdx.x;
    float v = x[(size_t)row * HD + h];
    red[h] = v * v;
    __syncthreads();
    #pragma unroll
    for (int off = 64; off > 0; off >>= 1) {
        if (h < off) red[h] += red[h + off];
        __syncthreads();
    }
    float inv = rsqrtf(red[0] * (1.0f / 128.0f) + 1e-6f);
    nrm[h] = v * inv * scale[h];
    __syncthreads();
    if (h < 64) {
        int t = row / hpt;
        int pos = (t < splitT) ? posA[t] : posB[t - splitT];
        float inv_freq = expf((float)h * (-13.815510557964274f / 64.0f));
        float ang = (float)pos * inv_freq;
        float c = cosf(ang), s = sinf(ang);
        float x1 = nrm[h], x2 = nrm[h + 64];
        x[(size_t)row * HD + h]      = x1 * c - x2 * s;
        x[(size_t)row * HD + h + 64] = x2 * c + x1 * s;
    }
}

// ---------------------------------------------------------------------------
// KV cache build. (unchanged)
// ---------------------------------------------------------------------------
__global__ __launch_bounds__(256)
void cache_scatter(const float* __restrict__ in_k, const float* __restrict__ in_v,
                   const float* __restrict__ k_rot, const float* __restrict__ v_new,
                   float* __restrict__ out_k, float* __restrict__ out_v,
                   const int* __restrict__ clp, const int* __restrict__ acp) {
    int cache_len = clp[0], actx = acp[0];
    int noise_start = cache_len + actx;
    int i = blockIdx.x * 256 + threadIdx.x;
    int n = i >> 17;
    int rem = i & 131071;
    int pos = rem >> 5;
    int h4 = (rem & 31) << 2;
    size_t co = ((size_t)(n * MAX_KV + pos)) * HD + h4;
    float4 kv, vv;
    if (pos >= noise_start && pos < noise_start + T_NOISE) {
        int srow = T_PAD + (pos - noise_start);
        size_t so = ((size_t)srow * KHD + (n >> 1)) * HD + h4;
        kv = *(const float4*)(k_rot + so);
        vv = *(const float4*)(v_new + so);
    } else if (pos >= cache_len && pos < cache_len + T_PAD) {
        int t = pos - cache_len;
        if (t < actx) {
            size_t so = ((size_t)t * KHD + (n >> 1)) * HD + h4;
            kv = *(const float4*)(k_rot + so);
            vv = *(const float4*)(v_new + so);
        } else {
            kv = make_float4(0.f, 0.f, 0.f, 0.f);
            vv = kv;
        }
    } else {
        kv = *(const float4*)(in_k + co);
        vv = *(const float4*)(in_v + co);
    }
    *(float4*)(out_k + co) = kv;
    *(float4*)(out_v + co) = vv;
}

// ---------------------------------------------------------------------------
// MFMA bf16 flash attention.
// Block = 256 threads (4 waves), one head, 64 q rows (wave w owns rows
// w*16..w*16+15). KV tiles of 32, double-buffered LDS, one barrier per tile.
//
// LDS layout (bytes), 38400 total:
//   KBUF(b)=b*8192       : K tile [32 rows][256B], 16B slots XOR-swizzled by row&7
//   VBUF(b)=16384+b*8448 : V tile as [ht=8][ks=8][4][16] bf16 subtiles,
//                          ht stride 1056B (=528 elems, de-banked), ks stride 128B
//   PBUF(w)=33280+w*1280 : per-wave P [16 rows][80B]
//
// mfma_f32_16x16x32_bf16 layouts used (guide §3, m89/m91-verified C/D):
//   A: lane holds row (l&15), k = 8*(l>>4)+i (k-contiguous, b128-loadable)
//   B: lane holds col (l&15), k = 8*(l>>4)+i
//   C/D: col = l&15, row = 4*(l>>4)+reg
// ---------------------------------------------------------------------------
#define KBUF(b) ((b) * 8192)
#define VBUF(b) (16384 + (b) * 8448)
#define PBUF(w) (33280 + (w) * 1280)

__device__ __forceinline__ unsigned short f2bf(float f) {
    union { float f; unsigned u; } v; v.f = f;
    unsigned r = v.u + 0x7fff + ((v.u >> 16) & 1);   // round-nearest-even
    return (unsigned short)(r >> 16);
}

__device__ __forceinline__ short4v tr_read(unsigned addr) {
    short4v d;
    asm volatile("ds_read_b64_tr_b16 %0, %1" : "=v"(d) : "v"(addr));
    return d;
}

__global__ __launch_bounds__(256)
void attn_mfma(const float* __restrict__ qrot, const float* __restrict__ kc,
               const float* __restrict__ vc, float* __restrict__ aout,
               const int* __restrict__ clp, const int* __restrict__ acp) {
    __shared__ __align__(16) char smem[38400];
    const int tid  = threadIdx.x;
    const int w    = tid >> 6;
    const int lane = tid & 63;
    const int g    = lane >> 4;
    const int li   = lane & 15;
    const int head = blockIdx.y;
    const int q0   = blockIdx.x * 64;
    const int new_len = clp[0] + acp[0] + T_NOISE;
    const int ntiles  = (new_len + 31) >> 5;

    const float* kbase = kc + (size_t)head * MAX_KV * HD;
    const float* vbase = vc + (size_t)head * MAX_KV * HD;

    // Q A-fragments (scale folded in): qf[ks], lane holds Q[li][32ks+8g+i]
    short8 qf[4];
    {
        const int qidx = q0 + w * 16 + li;
        const float* qp = qrot + ((size_t)qidx * NH + head) * HD;
        #pragma unroll
        for (int ks = 0; ks < 4; ++ks) {
            float4 f0 = *(const float4*)(qp + 32 * ks + 8 * g);
            float4 f1 = *(const float4*)(qp + 32 * ks + 8 * g + 4);
            short8 q;
            q[0] = (short)f2bf(f0.x * SM_SCALE); q[1] = (short)f2bf(f0.y * SM_SCALE);
            q[2] = (short)f2bf(f0.z * SM_SCALE); q[3] = (short)f2bf(f0.w * SM_SCALE);
            q[4] = (short)f2bf(f1.x * SM_SCALE); q[5] = (short)f2bf(f1.y * SM_SCALE);
            q[6] = (short)f2bf(f1.z * SM_SCALE); q[7] = (short)f2bf(f1.w * SM_SCALE);
            qf[ks] = q;
        }
    }

    f32x4 acc[8];                       // acc[n][r] = O[4g+r][16n+li]
    #pragma unroll
    for (int n = 0; n < 8; ++n) { acc[n][0] = 0.f; acc[n][1] = 0.f; acc[n][2] = 0.f; acc[n][3] = 0.f; }
    float mrow[4], lrow[4];
    #pragma unroll
    for (int r = 0; r < 4; ++r) { mrow[r] = -INFINITY; lrow[r] = 0.f; }

    // staging coords: thread covers K/V row skv, 16 h-cols starting at sh
    const int skv = tid >> 3;
    const int sh  = (tid & 7) << 4;

    float4 kpre[4], vpre[4];
    {
        const float* kp = kbase + (size_t)skv * HD + sh;
        const float* vp = vbase + (size_t)skv * HD + sh;
        #pragma unroll
        for (int j = 0; j < 4; ++j) { kpre[j] = ((const float4*)kp)[j]; vpre[j] = ((const float4*)vp)[j]; }
    }

    for (int t = 0; t < ntiles; ++t) {
        const int b = t & 1;
        // ---- stage tile t from prefetch regs (f32 -> bf16) ----
        {
            char* kb = smem + KBUF(b) + skv * 256;
            char* vb = smem + VBUF(b) + (tid & 7) * 1056 + (skv >> 2) * 128 + (skv & 3) * 32;
            #pragma unroll
            for (int j = 0; j < 4; ++j) {
                float4 f = kpre[j];
                short4v s; s[0] = (short)f2bf(f.x); s[1] = (short)f2bf(f.y);
                           s[2] = (short)f2bf(f.z); s[3] = (short)f2bf(f.w);
                int colbyte = sh * 2 + 8 * j;
                *(short4v*)(kb + (((colbyte >> 4) ^ (skv & 7)) << 4) + (colbyte & 15)) = s;
                float4 fv = vpre[j];
                short4v sv; sv[0] = (short)f2bf(fv.x); sv[1] = (short)f2bf(fv.y);
                            sv[2] = (short)f2bf(fv.z); sv[3] = (short)f2bf(fv.w);
                *(short4v*)(vb + 8 * j) = sv;
            }
        }
        __syncthreads();
        // ---- prefetch tile t+1 (overlaps with compute below) ----
        if (t + 1 < ntiles) {
            const int p0 = (t + 1) << 5;
            const float* kp = kbase + (size_t)(p0 + skv) * HD + sh;
            const float* vp = vbase + (size_t)(p0 + skv) * HD + sh;
            #pragma unroll
            for (int j = 0; j < 4; ++j) { kpre[j] = ((const float4*)kp)[j]; vpre[j] = ((const float4*)vp)[j]; }
        }
        // ---- QK^T: S[16 q][32 kv] ----
        const int pos0 = t << 5;
        f32x4 s0, s1;
        s0[0]=0.f; s0[1]=0.f; s0[2]=0.f; s0[3]=0.f; s1 = s0;
        {
            const char* kb = smem + KBUF(b);
            #pragma unroll
            for (int ks = 0; ks < 4; ++ks) {
                int slot = ((4 * ks + g) ^ (li & 7)) << 4;
                short8 k0 = *(const short8*)(kb + li * 256 + slot);
                short8 k1 = *(const short8*)(kb + (16 + li) * 256 + slot);
                s0 = __builtin_amdgcn_mfma_f32_16x16x32_bf16(qf[ks], k0, s0, 0, 0, 0);
                s1 = __builtin_amdgcn_mfma_f32_16x16x32_bf16(qf[ks], k1, s1, 0, 0, 0);
            }
        }
        // ---- mask + online softmax (rows 4g+r live on this lane) ----
        if (pos0 + li >= new_len)      { s0[0] = -1e30f; s0[1] = -1e30f; s0[2] = -1e30f; s0[3] = -1e30f; }
        if (pos0 + li + 16 >= new_len) { s1[0] = -1e30f; s1[1] = -1e30f; s1[2] = -1e30f; s1[3] = -1e30f; }
        float p0v[4], p1v[4], alpha[4];
        #pragma unroll
        for (int r = 0; r < 4; ++r) {
            float mx = fmaxf(s0[r], s1[r]);
            #pragma unroll
            for (int off = 1; off < 16; off <<= 1) mx = fmaxf(mx, __shfl_xor(mx, off, 16));
            float mn = fmaxf(mrow[r], mx);
            alpha[r] = __expf(mrow[r] - mn);
            p0v[r] = __expf(s0[r] - mn);
            p1v[r] = __expf(s1[r] - mn);
            float rs = p0v[r] + p1v[r];
            #pragma unroll
            for (int off = 1; off < 16; off <<= 1) rs += __shfl_xor(rs, off, 16);
            lrow[r] = lrow[r] * alpha[r] + rs;
            mrow[r] = mn;
        }
        #pragma unroll
        for (int n = 0; n < 8; ++n)
            #pragma unroll
            for (int r = 0; r < 4; ++r) acc[n][r] *= alpha[r];
        // ---- P -> wave-private LDS (re-layout C-frag -> A-frag) ----
        {
            char* pb = smem + PBUF(w);
            #pragma unroll
            for (int r = 0; r < 4; ++r) {
                *(unsigned short*)(pb + (4 * g + r) * 80 + li * 2)        = f2bf(p0v[r]);
                *(unsigned short*)(pb + (4 * g + r) * 80 + (16 + li) * 2) = f2bf(p1v[r]);
            }
        }
        short8 pa = *(const short8*)(smem + PBUF(w) + li * 80 + g * 16);
        // ---- V B-fragments via hardware transpose read ----
        const unsigned vb0 = (unsigned)(size_t)(smem + VBUF(b)) + g * 256 + li * 8;
        short4v vt[16];
        #pragma unroll
        for (int ht = 0; ht < 8; ++ht) {
            vt[2 * ht]     = tr_read(vb0 + ht * 1056);
            vt[2 * ht + 1] = tr_read(vb0 + ht * 1056 + 128);
        }
        asm volatile("s_waitcnt lgkmcnt(0)" ::: "memory");
        __builtin_amdgcn_sched_barrier(0);
        // ---- PV ----
        #pragma unroll
        for (int ht = 0; ht < 8; ++ht) {
            short8 vf = __builtin_shufflevector(vt[2 * ht], vt[2 * ht + 1],
                                                0, 1, 2, 3, 4, 5, 6, 7);
            acc[ht] = __builtin_amdgcn_mfma_f32_16x16x32_bf16(pa, vf, acc[ht], 0, 0, 0);
        }
        __syncthreads();
    }
    // ---- epilogue ----
    #pragma unroll
    for (int r = 0; r < 4; ++r) {
        const float inv = 1.0f / lrow[r];
        const int qi = q0 + w * 16 + 4 * g + r;
        #pragma unroll
        for (int n = 0; n < 8; ++n)
            aout[((size_t)qi * NH + head) * HD + 16 * n + li] = acc[n][r] * inv;
    }
}

// ---------------------------------------------------------------------------
extern "C" void kernel_launch(void* const* d_in, const int* in_sizes, int n_in,
                              void* d_out, int out_size, void* d_ws, size_t ws_size,
                              hipStream_t stream) {
    const float* x_noise       = (const float*)d_in[0];
    const float* target_hidden = (const float*)d_in[1];
    const int*   noise_pos     = (const int*)d_in[2];
    const int*   ctx_pos       = (const int*)d_in[3];
    const float* in_k          = (const float*)d_in[4];
    const float* in_v          = (const float*)d_in[5];
    const int*   clp           = (const int*)d_in[6];
    const int*   acp           = (const int*)d_in[7];
    const float* Wq            = (const float*)d_in[8];
    const float* Wk            = (const float*)d_in[9];
    const float* Wv            = (const float*)d_in[10];
    const float* Wo            = (const float*)d_in[11];
    const float* q_scale       = (const float*)d_in[12];
    const float* k_scale       = (const float*)d_in[13];

    float* out   = (float*)d_out;
    float* out_k = out + (size_t)T_NOISE * D;
    float* out_v = out_k + (size_t)NH * MAX_KV * HD;

    float* ws    = (float*)d_ws;
    float* q_tmp = ws;                       // [0,   2M) floats
    float* k_tmp = ws + 2u * 1024 * 1024;    // [2M,  4M)
    float* v_tmp = ws + 4u * 1024 * 1024;    // [4M,  6M)
    float* a_out = k_tmp;                    // dead after cache_scatter; reuse

    dim3 blk(256);
    gemm_f32<<<dim3(2048 / 64, 1024 / 64), blk, 0, stream>>>(
        x_noise, x_noise, 1024, Wq, q_tmp, 1024, 2048);
    gemm_f32<<<dim3(1024 / 64, 2048 / 64), blk, 0, stream>>>(
        target_hidden, x_noise, 1024, Wk, k_tmp, 2048, 1024);
    gemm_f32<<<dim3(1024 / 64, 2048 / 64), blk, 0, stream>>>(
        target_hidden, x_noise, 1024, Wv, v_tmp, 2048, 1024);
    rmsrope<<<1024 * 16, 128, 0, stream>>>(q_tmp, NH, noise_pos, noise_pos, 2048, q_scale);
    rmsrope<<<2048 * 8, 128, 0, stream>>>(k_tmp, KHD, ctx_pos, noise_pos, 1024, k_scale);
    cache_scatter<<<8192, 256, 0, stream>>>(in_k, in_v, k_tmp, v_tmp, out_k, out_v, clp, acp);
    attn_mfma<<<dim3(16, 16), blk, 0, stream>>>(q_tmp, out_k, out_v, a_out, clp, acp);
    gemm_f32<<<dim3(2048 / 64, 1024 / 64), blk, 0, stream>>>(
        a_out, a_out, 1024, Wo, out, 1024, 2048);
}

// Round 4
// 357.355 us; speedup vs baseline: 3.8957x; 2.0833x over previous
//
#include <hip/hip_runtime.h>
#include <hip/hip_bf16.h>
#include <math.h>

#define D 2048
#define NH 16
#define KHD 8
#define HD 128
#define T_NOISE 1024
#define T_PAD 1024
#define MAX_KV 4096
#define SM_SCALE 0.08838834764831845f  /* 1/sqrt(128) */

typedef __attribute__((ext_vector_type(8))) short short8;
typedef __attribute__((ext_vector_type(4))) short short4v;
typedef __attribute__((ext_vector_type(4))) float f32x4;

__device__ __forceinline__ unsigned short f2bf(float f) {
    union { float f; unsigned u; } v; v.f = f;
    unsigned r = v.u + 0x7fff + ((v.u >> 16) & 1);   // round-nearest-even
    return (unsigned short)(r >> 16);
}

__device__ __forceinline__ void gload16(const void* g, void* l) {
    __builtin_amdgcn_global_load_lds(
        (const __attribute__((address_space(1))) unsigned int*)g,
        (__attribute__((address_space(3))) unsigned int*)l, 16, 0, 0);
}

// ---------------------------------------------------------------------------
// Concat + cast f32 -> bf16. 8 elems/thread.
// ---------------------------------------------------------------------------
__global__ __launch_bounds__(256)
void cast_concat(const float* __restrict__ A0, const float* __restrict__ A1,
                 short* __restrict__ out, int splitElems) {
    int i = (blockIdx.x * 256 + threadIdx.x) * 8;
    const float* src = (i < splitElems) ? (A0 + i) : (A1 + (i - splitElems));
    float4 f0 = *(const float4*)src;
    float4 f1 = *(const float4*)(src + 4);
    short8 s;
    s[0] = (short)f2bf(f0.x); s[1] = (short)f2bf(f0.y);
    s[2] = (short)f2bf(f0.z); s[3] = (short)f2bf(f0.w);
    s[4] = (short)f2bf(f1.x); s[5] = (short)f2bf(f1.y);
    s[6] = (short)f2bf(f1.z); s[7] = (short)f2bf(f1.w);
    *(short8*)(out + i) = s;
}

// ---------------------------------------------------------------------------
// Convert + transpose: W f32 [R][C] -> Wt bf16 [C][R]. 64x64 LDS tile.
// ---------------------------------------------------------------------------
__global__ __launch_bounds__(256)
void conv_transpose(const float* __restrict__ W, short* __restrict__ Wt,
                    int R, int C) {
    __shared__ short t[64][72];
    int tid = threadIdx.x;
    int r0 = blockIdx.y * 64, c0 = blockIdx.x * 64;
    int rl = tid >> 4, cl4 = (tid & 15) * 4;
    #pragma unroll
    for (int j = 0; j < 4; ++j) {
        int r = rl + j * 16;
        float4 f = *(const float4*)(W + (size_t)(r0 + r) * C + c0 + cl4);
        t[cl4 + 0][r] = (short)f2bf(f.x);
        t[cl4 + 1][r] = (short)f2bf(f.y);
        t[cl4 + 2][r] = (short)f2bf(f.z);
        t[cl4 + 3][r] = (short)f2bf(f.w);
    }
    __syncthreads();
    #pragma unroll
    for (int j = 0; j < 2; ++j) {
        int idx = tid + j * 256;
        int cr = idx >> 3, rc8 = (idx & 7) * 8;
        *(short8*)(Wt + (size_t)(c0 + cr) * R + r0 + rc8) = *(const short8*)&t[cr][rc8];
    }
}

// ---------------------------------------------------------------------------
// bf16 MFMA GEMM (m97 structure): C[M,N] f32 = A[M,K]bf16 * Bt[N,K]bf16^T.
// 128x128 tile, BK=32, 256 threads = 4 waves in 2x2, global_load_lds staging
// into linear LDS, 2 barriers/K-step. Output col n < csplit -> C0[m][n],
// else C1[m][n-csplit]; both with leading dim ldc.
// ---------------------------------------------------------------------------
__global__ __launch_bounds__(256)
void gemm_bf16(const short* __restrict__ A, const short* __restrict__ Bt,
               float* __restrict__ C0, float* __restrict__ C1,
               int csplit, int ldc, int K, int M) {
    __shared__ __align__(16) short As[128 * 32];
    __shared__ __align__(16) short Bs[128 * 32];
    const int tid = threadIdx.x;
    const int w = tid >> 6, lane = tid & 63;
    const int g = lane >> 4, li = lane & 15;
    const int wr = w >> 1, wc = w & 1;
    const int m0 = blockIdx.y * 128, n0 = blockIdx.x * 128;

    f32x4 acc[4][4];
    #pragma unroll
    for (int mi = 0; mi < 4; ++mi)
        #pragma unroll
        for (int ni = 0; ni < 4; ++ni) {
            acc[mi][ni][0] = 0.f; acc[mi][ni][1] = 0.f;
            acc[mi][ni][2] = 0.f; acc[mi][ni][3] = 0.f;
        }

    for (int k0 = 0; k0 < K; k0 += 32) {
        // stage A,B tiles: 512 x 16B slots each; slot idx = i*256 + w*64 + lane
        #pragma unroll
        for (int i = 0; i < 2; ++i) {
            int idx = i * 256 + w * 64 + lane;
            int row = idx >> 2, slot = idx & 3;
            gload16(A + (size_t)(m0 + row) * K + k0 + slot * 8,
                    (char*)As + (size_t)(i * 256 + w * 64) * 16);
            gload16(Bt + (size_t)(n0 + row) * K + k0 + slot * 8,
                    (char*)Bs + (size_t)(i * 256 + w * 64) * 16);
        }
        __syncthreads();
        short8 af[4], bf[4];
        #pragma unroll
        for (int mi = 0; mi < 4; ++mi)
            af[mi] = *(const short8*)&As[(wr * 64 + mi * 16 + li) * 32 + g * 8];
        #pragma unroll
        for (int ni = 0; ni < 4; ++ni)
            bf[ni] = *(const short8*)&Bs[(wc * 64 + ni * 16 + li) * 32 + g * 8];
        #pragma unroll
        for (int mi = 0; mi < 4; ++mi)
            #pragma unroll
            for (int ni = 0; ni < 4; ++ni)
                acc[mi][ni] = __builtin_amdgcn_mfma_f32_16x16x32_bf16(
                    af[mi], bf[ni], acc[mi][ni], 0, 0, 0);
        __syncthreads();
    }
    // epilogue: C/D layout col=li, row=4g+r
    #pragma unroll
    for (int mi = 0; mi < 4; ++mi) {
        #pragma unroll
        for (int ni = 0; ni < 4; ++ni) {
            int n = n0 + wc * 64 + ni * 16 + li;
            float* cp; int cn;
            if (n < csplit) { cp = C0; cn = n; } else { cp = C1; cn = n - csplit; }
            #pragma unroll
            for (int r = 0; r < 4; ++r) {
                int m = m0 + wr * 64 + mi * 16 + 4 * g + r;
                cp[(size_t)m * ldc + cn] = acc[mi][ni][r];
            }
        }
    }
}

// ---------------------------------------------------------------------------
// Fused RMSNorm + RoPE, in place. (unchanged)
// ---------------------------------------------------------------------------
__global__ __launch_bounds__(128)
void rmsrope(float* __restrict__ x, int hpt,
             const int* __restrict__ posA, const int* __restrict__ posB,
             int splitT, const float* __restrict__ scale) {
    __shared__ float red[128];
    __shared__ float nrm[128];
    int row = blockIdx.x;
    int h = threadIdx.x;
    float v = x[(size_t)row * HD + h];
    red[h] = v * v;
    __syncthreads();
    #pragma unroll
    for (int off = 64; off > 0; off >>= 1) {
        if (h < off) red[h] += red[h + off];
        __syncthreads();
    }
    float inv = rsqrtf(red[0] * (1.0f / 128.0f) + 1e-6f);
    nrm[h] = v * inv * scale[h];
    __syncthreads();
    if (h < 64) {
        int t = row / hpt;
        int pos = (t < splitT) ? posA[t] : posB[t - splitT];
        float inv_freq = expf((float)h * (-13.815510557964274f / 64.0f));
        float ang = (float)pos * inv_freq;
        float c = cosf(ang), s = sinf(ang);
        float x1 = nrm[h], x2 = nrm[h + 64];
        x[(size_t)row * HD + h]      = x1 * c - x2 * s;
        x[(size_t)row * HD + h + 64] = x2 * c + x1 * s;
    }
}

// ---------------------------------------------------------------------------
// KV cache build. (unchanged)
// ---------------------------------------------------------------------------
__global__ __launch_bounds__(256)
void cache_scatter(const float* __restrict__ in_k, const float* __restrict__ in_v,
                   const float* __restrict__ k_rot, const float* __restrict__ v_new,
                   float* __restrict__ out_k, float* __restrict__ out_v,
                   const int* __restrict__ clp, const int* __restrict__ acp) {
    int cache_len = clp[0], actx = acp[0];
    int noise_start = cache_len + actx;
    int i = blockIdx.x * 256 + threadIdx.x;
    int n = i >> 17;
    int rem = i & 131071;
    int pos = rem >> 5;
    int h4 = (rem & 31) << 2;
    size_t co = ((size_t)(n * MAX_KV + pos)) * HD + h4;
    float4 kv, vv;
    if (pos >= noise_start && pos < noise_start + T_NOISE) {
        int srow = T_PAD + (pos - noise_start);
        size_t so = ((size_t)srow * KHD + (n >> 1)) * HD + h4;
        kv = *(const float4*)(k_rot + so);
        vv = *(const float4*)(v_new + so);
    } else if (pos >= cache_len && pos < cache_len + T_PAD) {
        int t = pos - cache_len;
        if (t < actx) {
            size_t so = ((size_t)t * KHD + (n >> 1)) * HD + h4;
            kv = *(const float4*)(k_rot + so);
            vv = *(const float4*)(v_new + so);
        } else {
            kv = make_float4(0.f, 0.f, 0.f, 0.f);
            vv = kv;
        }
    } else {
        kv = *(const float4*)(in_k + co);
        vv = *(const float4*)(in_v + co);
    }
    *(float4*)(out_k + co) = kv;
    *(float4*)(out_v + co) = vv;
}

// ---------------------------------------------------------------------------
// MFMA bf16 flash attention (unchanged except bf16 output for the O-GEMM).
// ---------------------------------------------------------------------------
#define KBUF(b) ((b) * 8192)
#define VBUF(b) (16384 + (b) * 8448)
#define PBUF(w) (33280 + (w) * 1280)

__device__ __forceinline__ short4v tr_read(unsigned addr) {
    short4v d;
    asm volatile("ds_read_b64_tr_b16 %0, %1" : "=v"(d) : "v"(addr));
    return d;
}

__global__ __launch_bounds__(256)
void attn_mfma(const float* __restrict__ qrot, const float* __restrict__ kc,
               const float* __restrict__ vc, short* __restrict__ aout,
               const int* __restrict__ clp, const int* __restrict__ acp) {
    __shared__ __align__(16) char smem[38400];
    const int tid  = threadIdx.x;
    const int w    = tid >> 6;
    const int lane = tid & 63;
    const int g    = lane >> 4;
    const int li   = lane & 15;
    const int head = blockIdx.y;
    const int q0   = blockIdx.x * 64;
    const int new_len = clp[0] + acp[0] + T_NOISE;
    const int ntiles  = (new_len + 31) >> 5;

    const float* kbase = kc + (size_t)head * MAX_KV * HD;
    const float* vbase = vc + (size_t)head * MAX_KV * HD;

    short8 qf[4];
    {
        const int qidx = q0 + w * 16 + li;
        const float* qp = qrot + ((size_t)qidx * NH + head) * HD;
        #pragma unroll
        for (int ks = 0; ks < 4; ++ks) {
            float4 f0 = *(const float4*)(qp + 32 * ks + 8 * g);
            float4 f1 = *(const float4*)(qp + 32 * ks + 8 * g + 4);
            short8 q;
            q[0] = (short)f2bf(f0.x * SM_SCALE); q[1] = (short)f2bf(f0.y * SM_SCALE);
            q[2] = (short)f2bf(f0.z * SM_SCALE); q[3] = (short)f2bf(f0.w * SM_SCALE);
            q[4] = (short)f2bf(f1.x * SM_SCALE); q[5] = (short)f2bf(f1.y * SM_SCALE);
            q[6] = (short)f2bf(f1.z * SM_SCALE); q[7] = (short)f2bf(f1.w * SM_SCALE);
            qf[ks] = q;
        }
    }

    f32x4 acc[8];
    #pragma unroll
    for (int n = 0; n < 8; ++n) { acc[n][0] = 0.f; acc[n][1] = 0.f; acc[n][2] = 0.f; acc[n][3] = 0.f; }
    float mrow[4], lrow[4];
    #pragma unroll
    for (int r = 0; r < 4; ++r) { mrow[r] = -INFINITY; lrow[r] = 0.f; }

    const int skv = tid >> 3;
    const int sh  = (tid & 7) << 4;

    float4 kpre[4], vpre[4];
    {
        const float* kp = kbase + (size_t)skv * HD + sh;
        const float* vp = vbase + (size_t)skv * HD + sh;
        #pragma unroll
        for (int j = 0; j < 4; ++j) { kpre[j] = ((const float4*)kp)[j]; vpre[j] = ((const float4*)vp)[j]; }
    }

    for (int t = 0; t < ntiles; ++t) {
        const int b = t & 1;
        {
            char* kb = smem + KBUF(b) + skv * 256;
            char* vb = smem + VBUF(b) + (tid & 7) * 1056 + (skv >> 2) * 128 + (skv & 3) * 32;
            #pragma unroll
            for (int j = 0; j < 4; ++j) {
                float4 f = kpre[j];
                short4v s; s[0] = (short)f2bf(f.x); s[1] = (short)f2bf(f.y);
                           s[2] = (short)f2bf(f.z); s[3] = (short)f2bf(f.w);
                int colbyte = sh * 2 + 8 * j;
                *(short4v*)(kb + (((colbyte >> 4) ^ (skv & 7)) << 4) + (colbyte & 15)) = s;
                float4 fv = vpre[j];
                short4v sv; sv[0] = (short)f2bf(fv.x); sv[1] = (short)f2bf(fv.y);
                            sv[2] = (short)f2bf(fv.z); sv[3] = (short)f2bf(fv.w);
                *(short4v*)(vb + 8 * j) = sv;
            }
        }
        __syncthreads();
        if (t + 1 < ntiles) {
            const int p0 = (t + 1) << 5;
            const float* kp = kbase + (size_t)(p0 + skv) * HD + sh;
            const float* vp = vbase + (size_t)(p0 + skv) * HD + sh;
            #pragma unroll
            for (int j = 0; j < 4; ++j) { kpre[j] = ((const float4*)kp)[j]; vpre[j] = ((const float4*)vp)[j]; }
        }
        const int pos0 = t << 5;
        f32x4 s0, s1;
        s0[0]=0.f; s0[1]=0.f; s0[2]=0.f; s0[3]=0.f; s1 = s0;
        {
            const char* kb = smem + KBUF(b);
            #pragma unroll
            for (int ks = 0; ks < 4; ++ks) {
                int slot = ((4 * ks + g) ^ (li & 7)) << 4;
                short8 k0 = *(const short8*)(kb + li * 256 + slot);
                short8 k1 = *(const short8*)(kb + (16 + li) * 256 + slot);
                s0 = __builtin_amdgcn_mfma_f32_16x16x32_bf16(qf[ks], k0, s0, 0, 0, 0);
                s1 = __builtin_amdgcn_mfma_f32_16x16x32_bf16(qf[ks], k1, s1, 0, 0, 0);
            }
        }
        if (pos0 + li >= new_len)      { s0[0] = -1e30f; s0[1] = -1e30f; s0[2] = -1e30f; s0[3] = -1e30f; }
        if (pos0 + li + 16 >= new_len) { s1[0] = -1e30f; s1[1] = -1e30f; s1[2] = -1e30f; s1[3] = -1e30f; }
        float p0v[4], p1v[4], alpha[4];
        #pragma unroll
        for (int r = 0; r < 4; ++r) {
            float mx = fmaxf(s0[r], s1[r]);
            #pragma unroll
            for (int off = 1; off < 16; off <<= 1) mx = fmaxf(mx, __shfl_xor(mx, off, 16));
            float mn = fmaxf(mrow[r], mx);
            alpha[r] = __expf(mrow[r] - mn);
            p0v[r] = __expf(s0[r] - mn);
            p1v[r] = __expf(s1[r] - mn);
            float rs = p0v[r] + p1v[r];
            #pragma unroll
            for (int off = 1; off < 16; off <<= 1) rs += __shfl_xor(rs, off, 16);
            lrow[r] = lrow[r] * alpha[r] + rs;
            mrow[r] = mn;
        }
        #pragma unroll
        for (int n = 0; n < 8; ++n)
            #pragma unroll
            for (int r = 0; r < 4; ++r) acc[n][r] *= alpha[r];
        {
            char* pb = smem + PBUF(w);
            #pragma unroll
            for (int r = 0; r < 4; ++r) {
                *(unsigned short*)(pb + (4 * g + r) * 80 + li * 2)        = f2bf(p0v[r]);
                *(unsigned short*)(pb + (4 * g + r) * 80 + (16 + li) * 2) = f2bf(p1v[r]);
            }
        }
        short8 pa = *(const short8*)(smem + PBUF(w) + li * 80 + g * 16);
        const unsigned vb0 = (unsigned)(size_t)(smem + VBUF(b)) + g * 256 + li * 8;
        short4v vt[16];
        #pragma unroll
        for (int ht = 0; ht < 8; ++ht) {
            vt[2 * ht]     = tr_read(vb0 + ht * 1056);
            vt[2 * ht + 1] = tr_read(vb0 + ht * 1056 + 128);
        }
        asm volatile("s_waitcnt lgkmcnt(0)" ::: "memory");
        __builtin_amdgcn_sched_barrier(0);
        #pragma unroll
        for (int ht = 0; ht < 8; ++ht) {
            short8 vf = __builtin_shufflevector(vt[2 * ht], vt[2 * ht + 1],
                                                0, 1, 2, 3, 4, 5, 6, 7);
            acc[ht] = __builtin_amdgcn_mfma_f32_16x16x32_bf16(pa, vf, acc[ht], 0, 0, 0);
        }
        __syncthreads();
    }
    #pragma unroll
    for (int r = 0; r < 4; ++r) {
        const float inv = 1.0f / lrow[r];
        const int qi = q0 + w * 16 + 4 * g + r;
        #pragma unroll
        for (int n = 0; n < 8; ++n)
            aout[((size_t)qi * NH + head) * HD + 16 * n + li] = (short)f2bf(acc[n][r] * inv);
    }
}

// ---------------------------------------------------------------------------
extern "C" void kernel_launch(void* const* d_in, const int* in_sizes, int n_in,
                              void* d_out, int out_size, void* d_ws, size_t ws_size,
                              hipStream_t stream) {
    const float* x_noise       = (const float*)d_in[0];
    const float* target_hidden = (const float*)d_in[1];
    const int*   noise_pos     = (const int*)d_in[2];
    const int*   ctx_pos       = (const int*)d_in[3];
    const float* in_k          = (const float*)d_in[4];
    const float* in_v          = (const float*)d_in[5];
    const int*   clp           = (const int*)d_in[6];
    const int*   acp           = (const int*)d_in[7];
    const float* Wq            = (const float*)d_in[8];
    const float* Wk            = (const float*)d_in[9];
    const float* Wv            = (const float*)d_in[10];
    const float* Wo            = (const float*)d_in[11];
    const float* q_scale       = (const float*)d_in[12];
    const float* k_scale       = (const float*)d_in[13];

    float* out   = (float*)d_out;
    float* out_k = out + (size_t)T_NOISE * D;
    float* out_v = out_k + (size_t)NH * MAX_KV * HD;

    float* ws    = (float*)d_ws;
    float* q_tmp = ws;                            // [0, 2M) floats
    float* k_tmp = ws + 2u * 1024 * 1024;         // [2M, 4M)
    float* v_tmp = ws + 4u * 1024 * 1024;         // [4M, 6M)
    short* xbf   = (short*)(ws + 6u * 1024 * 1024);   // 4M bf16 = [6M, 8M)
    short* a_bf  = xbf;                           // overlays xbf (dead after KV GEMM)
    short* wq_t  = (short*)(ws + 8u * 1024 * 1024);   // 4M bf16 = [8M, 10M)
    short* wk_t  = (short*)(ws + 10u * 1024 * 1024);  // 2M bf16 = [10M, 11M)
    short* wv_t  = wk_t + 1024 * 2048;                // 2M bf16 = [11M, 12M) (contiguous!)
    short* wo_t  = wk_t;                          // overlays wk/wv (dead after KV GEMM)

    dim3 blk(256);
    // bf16 conversions / transposes
    cast_concat<<<2048, blk, 0, stream>>>(target_hidden, x_noise, xbf, 1024 * 2048);
    conv_transpose<<<dim3(32, 32), blk, 0, stream>>>(Wq, wq_t, 2048, 2048);
    conv_transpose<<<dim3(16, 32), blk, 0, stream>>>(Wk, wk_t, 2048, 1024);
    conv_transpose<<<dim3(16, 32), blk, 0, stream>>>(Wv, wv_t, 2048, 1024);
    // Q projection: A = xbf rows 1024..2047 (x_noise)
    gemm_bf16<<<dim3(16, 8), blk, 0, stream>>>(
        xbf + (size_t)1024 * 2048, wq_t, q_tmp, q_tmp, 2048, 2048, 2048, 1024);
    // fused K|V projection: N=2048 (cols 0..1023 -> k_tmp, 1024..2047 -> v_tmp)
    gemm_bf16<<<dim3(16, 16), blk, 0, stream>>>(
        xbf, wk_t, k_tmp, v_tmp, 1024, 1024, 2048, 2048);
    // Wo transpose (after KV GEMM so it can overlay wk/wv region)
    conv_transpose<<<dim3(32, 32), blk, 0, stream>>>(Wo, wo_t, 2048, 2048);
    // Norm + RoPE
    rmsrope<<<1024 * 16, 128, 0, stream>>>(q_tmp, NH, noise_pos, noise_pos, 2048, q_scale);
    rmsrope<<<2048 * 8, 128, 0, stream>>>(k_tmp, KHD, ctx_pos, noise_pos, 1024, k_scale);
    // KV cache build
    cache_scatter<<<8192, 256, 0, stream>>>(in_k, in_v, k_tmp, v_tmp, out_k, out_v, clp, acp);
    // Attention -> bf16 (a_bf overlays xbf, dead by now)
    attn_mfma<<<dim3(16, 16), blk, 0, stream>>>(q_tmp, out_k, out_v, a_bf, clp, acp);
    // Output projection
    gemm_bf16<<<dim3(16, 8), blk, 0, stream>>>(
        a_bf, wo_t, out, out, 2048, 2048, 2048, 1024);
}